// Round 1
// baseline (801.990 us; speedup 1.0000x reference)
//
#include <hip/hip_runtime.h>
#include <hip/hip_bf16.h>

typedef __bf16 bf16;
typedef __bf16 bf16x8 __attribute__((ext_vector_type(8)));
typedef float  f32x4  __attribute__((ext_vector_type(4)));

#define DEVI __device__ __forceinline__

// Problem constants
// B_=2048 windows, N=64 tokens, C=256, H=8 heads, HD=32, NW=64 windows/image
static constexpr float kScale = 0.17677669529663687f;  // 32^-0.5

// ---------------- prep: transposed bf16 weights + fused rel-pos bias ----------------
// wqkvT[m][n][k] = w_m[k][n] * (m==0 ? scale : 1)     (m: 0=q 1=k 2=v)
// wpT[n][k]      = wp[k][n]
// bqkv[m][n]     = b_m[n]    * (m==0 ? scale : 1)
// biasF[h][i][j] = bias_table[rel_index[i][j]][h]
__global__ __launch_bounds__(256) void prep_kernel(
    const float* __restrict__ wq, const float* __restrict__ bq,
    const float* __restrict__ wk, const float* __restrict__ bk,
    const float* __restrict__ wv, const float* __restrict__ bv,
    const float* __restrict__ wp,
    const float* __restrict__ bias_table, const int* __restrict__ rel_index,
    bf16* __restrict__ wqkvT, bf16* __restrict__ wpT,
    float* __restrict__ bqkv, float* __restrict__ biasF) {
  int idx = blockIdx.x * 256 + threadIdx.x;
  if (idx < 196608) {                       // 3*256*256
    int m = idx >> 16, rem = idx & 65535;
    int n = rem >> 8, k = rem & 255;
    const float* w = (m == 0) ? wq : (m == 1 ? wk : wv);
    float v = w[k * 256 + n];
    if (m == 0) v *= kScale;
    wqkvT[idx] = (bf16)v;
  } else if (idx < 262144) {                // + 256*256
    int rem = idx - 196608;
    int n = rem >> 8, k = rem & 255;
    wpT[rem] = (bf16)wp[k * 256 + n];
  } else if (idx < 262912) {                // + 3*256
    int rem = idx - 262144;
    int m = rem >> 8, n = rem & 255;
    const float* b = (m == 0) ? bq : (m == 1 ? bk : bv);
    float v = b[n];
    if (m == 0) v *= kScale;
    bqkv[rem] = v;
  } else if (idx < 295680) {                // + 8*64*64
    int rem = idx - 262912;
    int h = rem >> 12, ij = rem & 4095;
    biasF[rem] = bias_table[rel_index[ij] * 8 + h];
  }
}

// ---------------- kernel A: fused QKV projection ----------------
// Block = 64 rows (one window), 4 waves; wave w owns rows 16w..16w+15.
// A-frag (16x32): lane holds row (lane&15), k = (lane>>4)*8 + e (contiguous 8)
// B-operand from transposed weights: lane holds col (lane&15), same contiguous k.
// C layout: col = lane&15, row = (lane>>4)*4 + reg   [guide §3, m89-verified]
__global__ __launch_bounds__(256) void qkv_kernel(
    const float* __restrict__ x, const bf16* __restrict__ wqkvT,
    const float* __restrict__ bqkv,
    bf16* __restrict__ qbuf, bf16* __restrict__ kbuf, bf16* __restrict__ vbuf) {
  int tid = threadIdx.x;
  int wv_ = tid >> 6, lane = tid & 63;
  int g = lane >> 4, c = lane & 15;

  long rowA = (long)blockIdx.x * 64 + wv_ * 16 + c;
  const float* xrow = x + rowA * 256;
  bf16x8 af[8];
#pragma unroll
  for (int kb = 0; kb < 8; ++kb) {
    const float4* p = (const float4*)(xrow + kb * 32 + g * 8);
    float4 f0 = p[0], f1 = p[1];
    bf16x8 a;
    a[0] = (bf16)f0.x; a[1] = (bf16)f0.y; a[2] = (bf16)f0.z; a[3] = (bf16)f0.w;
    a[4] = (bf16)f1.x; a[5] = (bf16)f1.y; a[6] = (bf16)f1.z; a[7] = (bf16)f1.w;
    af[kb] = a;
  }

  long rowbase = (long)blockIdx.x * 64 + wv_ * 16 + g * 4;
#pragma unroll
  for (int m = 0; m < 3; ++m) {
    bf16* dst = (m == 0) ? qbuf : (m == 1 ? kbuf : vbuf);
    f32x4 acc[16];
#pragma unroll
    for (int nt = 0; nt < 16; ++nt) {
      float b = bqkv[m * 256 + nt * 16 + c];
      f32x4 a = {b, b, b, b};
      acc[nt] = a;
    }
#pragma unroll
    for (int kb = 0; kb < 8; ++kb) {
#pragma unroll
      for (int nt = 0; nt < 16; ++nt) {
        const bf16x8* bp8 =
            (const bf16x8*)(wqkvT + ((m * 256 + nt * 16 + c) * 256 + kb * 32 + g * 8));
        acc[nt] = __builtin_amdgcn_mfma_f32_16x16x32_bf16(af[kb], *bp8, acc[nt], 0, 0, 0);
      }
    }
#pragma unroll
    for (int nt = 0; nt < 16; ++nt)
#pragma unroll
      for (int r = 0; r < 4; ++r)
        dst[(rowbase + r) * 256 + nt * 16 + c] = (bf16)acc[nt][r];
  }
}

// LDS swizzles (guide G4 / T2): spread row-strided accesses across banks;
// XOR hits addr bits 4..6 = j bits 3..5 -> bijective within a row.
DEVI int swzP(int i, int j2) {  // pbuf [64][64] bf16, rows 128B
  return (i * 128 + j2) ^ ((i & 7) << 4);
}
DEVI int swzV(int cc, int j2) { // vts [256][64] bf16, rows 128B
  return (cc * 128 + j2) ^ ((((cc & 7) ^ ((cc >> 3) & 7))) << 4);
}

// ---------------- kernel B: per-window attention ----------------
// Block = 1 window, 4 waves; wave w does heads {2w, 2w+1} over all 64 rows.
// QK^T: 16 tiles, one mfma each (K=32 = head dim). Softmax in-register,
// 16-lane shfl_xor row reduction. P and V^T staged through swizzled LDS
// for the PV operand relayout. Output overwrites qbuf (cols already consumed).
__global__ __launch_bounds__(256) void attn_kernel(
    const bf16* __restrict__ qbuf, const bf16* __restrict__ kbuf,
    const bf16* __restrict__ vbuf, const float* __restrict__ biasF,
    const float* __restrict__ mask, bf16* __restrict__ obuf) {
  __shared__ __align__(16) char vts[32768];   // V^T [256][64] bf16, swizzled
  __shared__ __align__(16) char pbuf[32768];  // per-wave P [64][64] bf16, swizzled

  int tid = threadIdx.x;
  int wv_ = tid >> 6, lane = tid & 63;
  int g = lane >> 4, c = lane & 15;
  int win = blockIdx.x;
  const float* maskw = mask + (size_t)(win & 63) * 4096;

  // stage V^T: coalesced 16B reads, swizzled 2B LDS writes
  {
    int jb = tid >> 5;           // 0..7
    int c0 = (tid & 31) * 8;     // 0..248
#pragma unroll
    for (int rep = 0; rep < 8; ++rep) {
      int j = jb + rep * 8;
      bf16x8 v8 = *(const bf16x8*)(vbuf + ((long)win * 64 + j) * 256 + c0);
#pragma unroll
      for (int e = 0; e < 8; ++e)
        *(bf16*)(vts + swzV(c0 + e, 2 * j)) = v8[e];
    }
  }
  __syncthreads();

  char* pb = pbuf + wv_ * 8192;
  const f32x4 fzero = {0.f, 0.f, 0.f, 0.f};

  for (int hh = 0; hh < 2; ++hh) {
    int h = wv_ * 2 + hh;
    // Q,K fragments straight from global (16B contiguous per lane)
    bf16x8 qf[4], kf[4];
#pragma unroll
    for (int mi = 0; mi < 4; ++mi) {
      long row = (long)win * 64 + mi * 16 + c;
      qf[mi] = *(const bf16x8*)(qbuf + row * 256 + h * 32 + g * 8);
      kf[mi] = *(const bf16x8*)(kbuf + row * 256 + h * 32 + g * 8);
    }
    f32x4 s[4][4];
#pragma unroll
    for (int mi = 0; mi < 4; ++mi)
#pragma unroll
      for (int mj = 0; mj < 4; ++mj)
        s[mi][mj] = __builtin_amdgcn_mfma_f32_16x16x32_bf16(qf[mi], kf[mj], fzero, 0, 0, 0);

    // + rel-pos bias + window mask, then row softmax
    const float* bh = biasF + (size_t)h * 4096;
#pragma unroll
    for (int mi = 0; mi < 4; ++mi) {
#pragma unroll
      for (int r = 0; r < 4; ++r) {
        int i = mi * 16 + g * 4 + r;
        float mx = -3.0e38f;
#pragma unroll
        for (int mj = 0; mj < 4; ++mj) {
          int j = mj * 16 + c;
          float val = s[mi][mj][r] + bh[i * 64 + j] + maskw[i * 64 + j];
          s[mi][mj][r] = val;
          mx = fmaxf(mx, val);
        }
        mx = fmaxf(mx, __shfl_xor(mx, 1));
        mx = fmaxf(mx, __shfl_xor(mx, 2));
        mx = fmaxf(mx, __shfl_xor(mx, 4));
        mx = fmaxf(mx, __shfl_xor(mx, 8));
        float sum = 0.f;
#pragma unroll
        for (int mj = 0; mj < 4; ++mj) {
          float p = __expf(s[mi][mj][r] - mx);
          s[mi][mj][r] = p;
          sum += p;
        }
        sum += __shfl_xor(sum, 1);
        sum += __shfl_xor(sum, 2);
        sum += __shfl_xor(sum, 4);
        sum += __shfl_xor(sum, 8);
        float rs = 1.0f / sum;
#pragma unroll
        for (int mj = 0; mj < 4; ++mj) s[mi][mj][r] *= rs;
      }
    }

    // P -> wave-private LDS (bf16, swizzled); same-wave ds ops are in-order
#pragma unroll
    for (int mi = 0; mi < 4; ++mi)
#pragma unroll
      for (int mj = 0; mj < 4; ++mj)
#pragma unroll
        for (int r = 0; r < 4; ++r) {
          int i = mi * 16 + g * 4 + r, j = mj * 16 + c;
          *(bf16*)(pb + swzP(i, 2 * j)) = (bf16)s[mi][mj][r];
        }

    // PV: out[i][d] += P[i][j] * V[j][d], K=64 in two k-steps
    f32x4 o[4][2];
#pragma unroll
    for (int mi = 0; mi < 4; ++mi)
#pragma unroll
      for (int dt = 0; dt < 2; ++dt) o[mi][dt] = fzero;
#pragma unroll
    for (int mi = 0; mi < 4; ++mi) {
#pragma unroll
      for (int kb = 0; kb < 2; ++kb) {
        int i = mi * 16 + c;
        int j2 = 2 * (kb * 32 + g * 8);
        bf16x8 pa = *(const bf16x8*)(pb + swzP(i, j2));
#pragma unroll
        for (int dt = 0; dt < 2; ++dt) {
          int cc = h * 32 + dt * 16 + c;
          bf16x8 vb = *(const bf16x8*)(vts + swzV(cc, j2));
          o[mi][dt] = __builtin_amdgcn_mfma_f32_16x16x32_bf16(pa, vb, o[mi][dt], 0, 0, 0);
        }
      }
    }
    // store attention output into qbuf region (this head's q cols are dead)
#pragma unroll
    for (int mi = 0; mi < 4; ++mi)
#pragma unroll
      for (int dt = 0; dt < 2; ++dt)
#pragma unroll
        for (int r = 0; r < 4; ++r) {
          long row = (long)win * 64 + mi * 16 + g * 4 + r;
          obuf[row * 256 + h * 32 + dt * 16 + c] = (bf16)o[mi][dt][r];
        }
  }
}

// ---------------- kernel C: output projection ----------------
__global__ __launch_bounds__(256) void proj_kernel(
    const bf16* __restrict__ abuf, const bf16* __restrict__ wpT,
    const float* __restrict__ bp, float* __restrict__ out) {
  int tid = threadIdx.x;
  int wv_ = tid >> 6, lane = tid & 63;
  int g = lane >> 4, c = lane & 15;

  long rowA = (long)blockIdx.x * 64 + wv_ * 16 + c;
  bf16x8 af[8];
#pragma unroll
  for (int kb = 0; kb < 8; ++kb)
    af[kb] = *(const bf16x8*)(abuf + rowA * 256 + kb * 32 + g * 8);

  f32x4 acc[16];
#pragma unroll
  for (int nt = 0; nt < 16; ++nt) {
    float b = bp[nt * 16 + c];
    f32x4 a = {b, b, b, b};
    acc[nt] = a;
  }
#pragma unroll
  for (int kb = 0; kb < 8; ++kb)
#pragma unroll
    for (int nt = 0; nt < 16; ++nt) {
      const bf16x8* bfr = (const bf16x8*)(wpT + ((nt * 16 + c) * 256 + kb * 32 + g * 8));
      acc[nt] = __builtin_amdgcn_mfma_f32_16x16x32_bf16(af[kb], *bfr, acc[nt], 0, 0, 0);
    }

  long rowbase = (long)blockIdx.x * 64 + wv_ * 16 + g * 4;
#pragma unroll
  for (int nt = 0; nt < 16; ++nt)
#pragma unroll
    for (int r = 0; r < 4; ++r)
      out[(rowbase + r) * 256 + nt * 16 + c] = acc[nt][r];
}

extern "C" void kernel_launch(void* const* d_in, const int* in_sizes, int n_in,
                              void* d_out, int out_size, void* d_ws, size_t ws_size,
                              hipStream_t stream) {
  const float* x          = (const float*)d_in[0];
  const float* mask       = (const float*)d_in[1];
  const float* wq         = (const float*)d_in[2];
  const float* bq         = (const float*)d_in[3];
  const float* wk         = (const float*)d_in[4];
  const float* bk         = (const float*)d_in[5];
  const float* wv         = (const float*)d_in[6];
  const float* bv         = (const float*)d_in[7];
  const float* wp         = (const float*)d_in[8];
  const float* bp         = (const float*)d_in[9];
  const float* bias_table = (const float*)d_in[10];
  const int*   rel_index  = (const int*)d_in[11];

  // Workspace layout (needs ~68 MB):
  //   qbuf (64 MB, reused as attention-output buffer) | wqkvT | wpT | bqkv | biasF
  char* ws = (char*)d_ws;
  size_t o = 0;
  bf16* qbuf = (bf16*)(ws + o); o += (size_t)2048 * 64 * 256 * 2;
  bf16* wqkvT = (bf16*)(ws + o); o += (size_t)3 * 256 * 256 * 2;
  bf16* wpT = (bf16*)(ws + o); o += (size_t)256 * 256 * 2;
  float* bqkv = (float*)(ws + o); o += (size_t)3 * 256 * 4;
  float* biasF = (float*)(ws + o); o += (size_t)8 * 64 * 64 * 4;
  if (ws_size < o) return;  // workspace too small -> fail loudly via validation

  // k,v live in d_out (128 MB fp32); both are dead before proj_kernel overwrites.
  bf16* vbuf = (bf16*)d_out;
  bf16* kbuf = vbuf + (size_t)2048 * 64 * 256;

  prep_kernel<<<1155, 256, 0, stream>>>(wq, bq, wk, bk, wv, bv, wp,
                                        bias_table, rel_index, wqkvT, wpT, bqkv, biasF);
  qkv_kernel<<<2048, 256, 0, stream>>>(x, wqkvT, bqkv, qbuf, kbuf, vbuf);
  attn_kernel<<<2048, 256, 0, stream>>>(qbuf, kbuf, vbuf, biasF, mask, qbuf);
  proj_kernel<<<2048, 256, 0, stream>>>(qbuf, wpT, bp, (float*)d_out);
}

// Round 2
// 357.052 us; speedup vs baseline: 2.2461x; 2.2461x over previous
//
#include <hip/hip_runtime.h>
#include <hip/hip_bf16.h>

typedef __bf16 bf16;
typedef __bf16 bf16x8 __attribute__((ext_vector_type(8)));
typedef float  f32x4  __attribute__((ext_vector_type(4)));

#define DEVI __device__ __forceinline__

// B_=2048 windows, N=64 tokens, C=256, H=8 heads, HD=32, NW=64 windows/image
static constexpr float kScale = 0.17677669529663687f;  // 32^-0.5

// Swizzled weight layout (both wqkvT and wpT):
//   conceptually [chunk][64 rows][512 B]; chunk = 64 output-cols x 256 k (bf16).
//   For weight output-col n, k: chunk-local row j = n & 63, byte b = 2*k stored at
//   chunk*32768 + j*512 + (b ^ ((j&7)<<4)).  XOR on bits 4..6 spreads the
//   row-strided ds_read_b128 fragment reads across banks (G4/T2), and the
//   compute-side read applies the same involution.
DEVI size_t wswz(int chunk, int j, int b) {
  return (size_t)chunk * 32768 + (size_t)j * 512 + (size_t)(b ^ ((j & 7) << 4));
}

// ---------------- prep: swizzled bf16 weights + fused rel-pos bias ----------------
__global__ __launch_bounds__(256) void prep_kernel(
    const float* __restrict__ wq, const float* __restrict__ bq,
    const float* __restrict__ wk, const float* __restrict__ bk,
    const float* __restrict__ wv, const float* __restrict__ bv,
    const float* __restrict__ wp,
    const float* __restrict__ bias_table, const int* __restrict__ rel_index,
    char* __restrict__ wqkvT, char* __restrict__ wpT,
    float* __restrict__ bqkv, float* __restrict__ biasF) {
  int idx = blockIdx.x * 256 + threadIdx.x;
  if (idx < 196608) {                       // 3*256*256  qkv weights
    int m = idx >> 16, rem = idx & 65535;
    int n = rem >> 8, k = rem & 255;
    const float* w = (m == 0) ? wq : (m == 1 ? wk : wv);
    float v = w[k * 256 + n];
    if (m == 0) v *= kScale;
    *(bf16*)(wqkvT + wswz(m * 4 + (n >> 6), n & 63, 2 * k)) = (bf16)v;
  } else if (idx < 262144) {                // + 256*256  proj weight
    int rem = idx - 196608;
    int n = rem >> 8, k = rem & 255;
    *(bf16*)(wpT + wswz(n >> 6, n & 63, 2 * k)) = (bf16)wp[k * 256 + n];
  } else if (idx < 262912) {                // + 3*256 biases
    int rem = idx - 262144;
    int m = rem >> 8, n = rem & 255;
    const float* b = (m == 0) ? bq : (m == 1 ? bk : bv);
    float v = b[n];
    if (m == 0) v *= kScale;
    bqkv[rem] = v;
  } else if (idx < 295680) {                // + 8*64*64 fused bias
    int rem = idx - 262912;
    int h = rem >> 12, ij = rem & 4095;
    biasF[rem] = bias_table[rel_index[ij] * 8 + h];
  }
}

// ---------------- kernel A: fused QKV projection (LDS-staged B) ----------------
// Block = 128 rows (2 windows), 4 waves; wave w owns rows w*32..w*32+31.
// A (x rows, K=256) held in registers for the whole kernel -> x read exactly once.
// B streamed through one 32 KB LDS chunk (64 cols x 256 k) per iteration, 12 chunks
// (3 matrices x 4 col-quarters). T14 split: issue next chunk's global loads right
// after the ds_writes, so HBM/L2 latency hides under this chunk's 64 MFMAs/wave.
__global__ __launch_bounds__(256) void qkv_kernel(
    const float* __restrict__ x, const char* __restrict__ wsz,
    const float* __restrict__ bqkv,
    bf16* __restrict__ qbuf, bf16* __restrict__ kbuf, bf16* __restrict__ vbuf) {
  __shared__ __align__(16) char bsm[32768];
  int tid = threadIdx.x;
  int w = tid >> 6, lane = tid & 63;
  int g = lane >> 4, c = lane & 15;
  size_t rowbase = (size_t)blockIdx.x * 128;

  // A fragments: af[rt][kb], row = rowbase + w*32 + rt*16 + c, k = kb*32+g*8+e
  bf16x8 af[2][8];
#pragma unroll
  for (int rt = 0; rt < 2; ++rt) {
    const float* xrow = x + (rowbase + w * 32 + rt * 16 + c) * 256;
#pragma unroll
    for (int kb = 0; kb < 8; ++kb) {
      const float4* p = (const float4*)(xrow + kb * 32 + g * 8);
      float4 f0 = p[0], f1 = p[1];
      bf16x8 a;
      a[0] = (bf16)f0.x; a[1] = (bf16)f0.y; a[2] = (bf16)f0.z; a[3] = (bf16)f0.w;
      a[4] = (bf16)f1.x; a[5] = (bf16)f1.y; a[6] = (bf16)f1.z; a[7] = (bf16)f1.w;
      af[rt][kb] = a;
    }
  }

  bf16x8 gr[8];  // staging regs: thread t covers bytes i*4096 + t*16 (coalesced)
#pragma unroll
  for (int i = 0; i < 8; ++i)
    gr[i] = *(const bf16x8*)(wsz + (size_t)i * 4096 + (size_t)tid * 16);

  for (int cc = 0; cc < 12; ++cc) {
    int m = cc >> 2, nq = cc & 3;
    __syncthreads();  // all waves done reading previous chunk
#pragma unroll
    for (int i = 0; i < 8; ++i)
      *(bf16x8*)(bsm + i * 4096 + tid * 16) = gr[i];
    if (cc < 11) {
      size_t base = (size_t)(cc + 1) * 32768;
#pragma unroll
      for (int i = 0; i < 8; ++i)
        gr[i] = *(const bf16x8*)(wsz + base + (size_t)i * 4096 + (size_t)tid * 16);
    }
    __syncthreads();  // chunk visible

    f32x4 acc[2][4];
#pragma unroll
    for (int ct = 0; ct < 4; ++ct) {
      float b = bqkv[m * 256 + nq * 64 + ct * 16 + c];
      f32x4 a = {b, b, b, b};
      acc[0][ct] = a; acc[1][ct] = a;
    }
#pragma unroll
    for (int kb = 0; kb < 8; ++kb) {
      bf16x8 bf[4];
#pragma unroll
      for (int ct = 0; ct < 4; ++ct) {
        int j = ct * 16 + c;
        int off = (kb * 64 + g * 16) ^ ((j & 7) << 4);
        bf[ct] = *(const bf16x8*)(bsm + j * 512 + off);
      }
#pragma unroll
      for (int rt = 0; rt < 2; ++rt)
#pragma unroll
        for (int ct = 0; ct < 4; ++ct)
          acc[rt][ct] = __builtin_amdgcn_mfma_f32_16x16x32_bf16(af[rt][kb], bf[ct], acc[rt][ct], 0, 0, 0);
    }

    bf16* dst = (m == 0) ? qbuf : (m == 1 ? kbuf : vbuf);
#pragma unroll
    for (int rt = 0; rt < 2; ++rt)
#pragma unroll
      for (int ct = 0; ct < 4; ++ct)
#pragma unroll
        for (int r = 0; r < 4; ++r)
          dst[(rowbase + w * 32 + rt * 16 + g * 4 + r) * 256 + nq * 64 + ct * 16 + c] =
              (bf16)acc[rt][ct][r];
  }
}

// LDS swizzles for attention staging buffers
DEVI int swzP(int i, int j2) {  // pbuf [64][64] bf16, rows 128B
  return (i * 128 + j2) ^ ((i & 7) << 4);
}
DEVI int swzV(int cc, int j2) { // vts [256][64] bf16, rows 128B
  return (cc * 128 + j2) ^ ((((cc & 7) ^ ((cc >> 3) & 7))) << 4);
}

// ---------------- kernel B: per-window attention (unchanged from R0) ----------------
__global__ __launch_bounds__(256) void attn_kernel(
    const bf16* __restrict__ qbuf, const bf16* __restrict__ kbuf,
    const bf16* __restrict__ vbuf, const float* __restrict__ biasF,
    const float* __restrict__ mask, bf16* __restrict__ obuf) {
  __shared__ __align__(16) char vts[32768];   // V^T [256][64] bf16, swizzled
  __shared__ __align__(16) char pbuf[32768];  // per-wave P [64][64] bf16, swizzled

  int tid = threadIdx.x;
  int wv_ = tid >> 6, lane = tid & 63;
  int g = lane >> 4, c = lane & 15;
  int win = blockIdx.x;
  const float* maskw = mask + (size_t)(win & 63) * 4096;

  {
    int jb = tid >> 5;
    int c0 = (tid & 31) * 8;
#pragma unroll
    for (int rep = 0; rep < 8; ++rep) {
      int j = jb + rep * 8;
      bf16x8 v8 = *(const bf16x8*)(vbuf + ((long)win * 64 + j) * 256 + c0);
#pragma unroll
      for (int e = 0; e < 8; ++e)
        *(bf16*)(vts + swzV(c0 + e, 2 * j)) = v8[e];
    }
  }
  __syncthreads();

  char* pb = pbuf + wv_ * 8192;
  const f32x4 fzero = {0.f, 0.f, 0.f, 0.f};

  for (int hh = 0; hh < 2; ++hh) {
    int h = wv_ * 2 + hh;
    bf16x8 qf[4], kf[4];
#pragma unroll
    for (int mi = 0; mi < 4; ++mi) {
      long row = (long)win * 64 + mi * 16 + c;
      qf[mi] = *(const bf16x8*)(qbuf + row * 256 + h * 32 + g * 8);
      kf[mi] = *(const bf16x8*)(kbuf + row * 256 + h * 32 + g * 8);
    }
    f32x4 s[4][4];
#pragma unroll
    for (int mi = 0; mi < 4; ++mi)
#pragma unroll
      for (int mj = 0; mj < 4; ++mj)
        s[mi][mj] = __builtin_amdgcn_mfma_f32_16x16x32_bf16(qf[mi], kf[mj], fzero, 0, 0, 0);

    const float* bh = biasF + (size_t)h * 4096;
#pragma unroll
    for (int mi = 0; mi < 4; ++mi) {
#pragma unroll
      for (int r = 0; r < 4; ++r) {
        int i = mi * 16 + g * 4 + r;
        float mx = -3.0e38f;
#pragma unroll
        for (int mj = 0; mj < 4; ++mj) {
          int j = mj * 16 + c;
          float val = s[mi][mj][r] + bh[i * 64 + j] + maskw[i * 64 + j];
          s[mi][mj][r] = val;
          mx = fmaxf(mx, val);
        }
        mx = fmaxf(mx, __shfl_xor(mx, 1));
        mx = fmaxf(mx, __shfl_xor(mx, 2));
        mx = fmaxf(mx, __shfl_xor(mx, 4));
        mx = fmaxf(mx, __shfl_xor(mx, 8));
        float sum = 0.f;
#pragma unroll
        for (int mj = 0; mj < 4; ++mj) {
          float p = __expf(s[mi][mj][r] - mx);
          s[mi][mj][r] = p;
          sum += p;
        }
        sum += __shfl_xor(sum, 1);
        sum += __shfl_xor(sum, 2);
        sum += __shfl_xor(sum, 4);
        sum += __shfl_xor(sum, 8);
        float rs = 1.0f / sum;
#pragma unroll
        for (int mj = 0; mj < 4; ++mj) s[mi][mj][r] *= rs;
      }
    }

#pragma unroll
    for (int mi = 0; mi < 4; ++mi)
#pragma unroll
      for (int mj = 0; mj < 4; ++mj)
#pragma unroll
        for (int r = 0; r < 4; ++r) {
          int i = mi * 16 + g * 4 + r, j = mj * 16 + c;
          *(bf16*)(pb + swzP(i, 2 * j)) = (bf16)s[mi][mj][r];
        }

    f32x4 o[4][2];
#pragma unroll
    for (int mi = 0; mi < 4; ++mi)
#pragma unroll
      for (int dt = 0; dt < 2; ++dt) o[mi][dt] = fzero;
#pragma unroll
    for (int mi = 0; mi < 4; ++mi) {
#pragma unroll
      for (int kb = 0; kb < 2; ++kb) {
        int i = mi * 16 + c;
        int j2 = 2 * (kb * 32 + g * 8);
        bf16x8 pa = *(const bf16x8*)(pb + swzP(i, j2));
#pragma unroll
        for (int dt = 0; dt < 2; ++dt) {
          int cc2 = h * 32 + dt * 16 + c;
          bf16x8 vb = *(const bf16x8*)(vts + swzV(cc2, j2));
          o[mi][dt] = __builtin_amdgcn_mfma_f32_16x16x32_bf16(pa, vb, o[mi][dt], 0, 0, 0);
        }
      }
    }
#pragma unroll
    for (int mi = 0; mi < 4; ++mi)
#pragma unroll
      for (int dt = 0; dt < 2; ++dt)
#pragma unroll
        for (int r = 0; r < 4; ++r) {
          long row = (long)win * 64 + mi * 16 + g * 4 + r;
          obuf[row * 256 + h * 32 + dt * 16 + c] = (bf16)o[mi][dt][r];
        }
  }
}

// ---------------- kernel C: output projection (LDS-staged B) ----------------
__global__ __launch_bounds__(256) void proj_kernel(
    const bf16* __restrict__ abuf, const char* __restrict__ wsz,
    const float* __restrict__ bp, float* __restrict__ out) {
  __shared__ __align__(16) char bsm[32768];
  int tid = threadIdx.x;
  int w = tid >> 6, lane = tid & 63;
  int g = lane >> 4, c = lane & 15;
  size_t rowbase = (size_t)blockIdx.x * 128;

  bf16x8 af[2][8];
#pragma unroll
  for (int rt = 0; rt < 2; ++rt) {
    const bf16* arow = abuf + (rowbase + w * 32 + rt * 16 + c) * 256;
#pragma unroll
    for (int kb = 0; kb < 8; ++kb)
      af[rt][kb] = *(const bf16x8*)(arow + kb * 32 + g * 8);
  }

  bf16x8 gr[8];
#pragma unroll
  for (int i = 0; i < 8; ++i)
    gr[i] = *(const bf16x8*)(wsz + (size_t)i * 4096 + (size_t)tid * 16);

  for (int cc = 0; cc < 4; ++cc) {
    __syncthreads();
#pragma unroll
    for (int i = 0; i < 8; ++i)
      *(bf16x8*)(bsm + i * 4096 + tid * 16) = gr[i];
    if (cc < 3) {
      size_t base = (size_t)(cc + 1) * 32768;
#pragma unroll
      for (int i = 0; i < 8; ++i)
        gr[i] = *(const bf16x8*)(wsz + base + (size_t)i * 4096 + (size_t)tid * 16);
    }
    __syncthreads();

    f32x4 acc[2][4];
#pragma unroll
    for (int ct = 0; ct < 4; ++ct) {
      float b = bp[cc * 64 + ct * 16 + c];
      f32x4 a = {b, b, b, b};
      acc[0][ct] = a; acc[1][ct] = a;
    }
#pragma unroll
    for (int kb = 0; kb < 8; ++kb) {
      bf16x8 bf[4];
#pragma unroll
      for (int ct = 0; ct < 4; ++ct) {
        int j = ct * 16 + c;
        int off = (kb * 64 + g * 16) ^ ((j & 7) << 4);
        bf[ct] = *(const bf16x8*)(bsm + j * 512 + off);
      }
#pragma unroll
      for (int rt = 0; rt < 2; ++rt)
#pragma unroll
        for (int ct = 0; ct < 4; ++ct)
          acc[rt][ct] = __builtin_amdgcn_mfma_f32_16x16x32_bf16(af[rt][kb], bf[ct], acc[rt][ct], 0, 0, 0);
    }

#pragma unroll
    for (int rt = 0; rt < 2; ++rt)
#pragma unroll
      for (int ct = 0; ct < 4; ++ct)
#pragma unroll
        for (int r = 0; r < 4; ++r)
          out[(rowbase + w * 32 + rt * 16 + g * 4 + r) * 256 + cc * 64 + ct * 16 + c] =
              acc[rt][ct][r];
  }
}

extern "C" void kernel_launch(void* const* d_in, const int* in_sizes, int n_in,
                              void* d_out, int out_size, void* d_ws, size_t ws_size,
                              hipStream_t stream) {
  const float* x          = (const float*)d_in[0];
  const float* mask       = (const float*)d_in[1];
  const float* wq         = (const float*)d_in[2];
  const float* bq         = (const float*)d_in[3];
  const float* wk         = (const float*)d_in[4];
  const float* bk         = (const float*)d_in[5];
  const float* wv         = (const float*)d_in[6];
  const float* bv         = (const float*)d_in[7];
  const float* wp         = (const float*)d_in[8];
  const float* bp         = (const float*)d_in[9];
  const float* bias_table = (const float*)d_in[10];
  const int*   rel_index  = (const int*)d_in[11];

  // Workspace: qbuf (64 MB, reused as attention-output) | wqkvT | wpT | bqkv | biasF
  char* ws = (char*)d_ws;
  size_t o = 0;
  bf16* qbuf = (bf16*)(ws + o); o += (size_t)2048 * 64 * 256 * 2;
  char* wqkvT = ws + o; o += (size_t)3 * 256 * 256 * 2;
  char* wpT = ws + o; o += (size_t)256 * 256 * 2;
  float* bqkv = (float*)(ws + o); o += (size_t)3 * 256 * 4;
  float* biasF = (float*)(ws + o); o += (size_t)8 * 64 * 64 * 4;
  if (ws_size < o) return;

  // k,v live in d_out (128 MB fp32); both dead before proj_kernel overwrites.
  bf16* vbuf = (bf16*)d_out;
  bf16* kbuf = vbuf + (size_t)2048 * 64 * 256;

  prep_kernel<<<1155, 256, 0, stream>>>(wq, bq, wk, bk, wv, bv, wp,
                                        bias_table, rel_index, wqkvT, wpT, bqkv, biasF);
  qkv_kernel<<<1024, 256, 0, stream>>>(x, wqkvT, bqkv, qbuf, kbuf, vbuf);
  attn_kernel<<<2048, 256, 0, stream>>>(qbuf, kbuf, vbuf, biasF, mask, qbuf);
  proj_kernel<<<1024, 256, 0, stream>>>(qbuf, wpT, bp, (float*)d_out);
}

// Round 3
// 215.322 us; speedup vs baseline: 3.7246x; 1.6582x over previous
//
#include <hip/hip_runtime.h>
#include <hip/hip_bf16.h>

typedef __bf16 bf16;
typedef __bf16 bf16x4 __attribute__((ext_vector_type(4)));
typedef __bf16 bf16x8 __attribute__((ext_vector_type(8)));
typedef float  f32x4  __attribute__((ext_vector_type(4)));

#define DEVI __device__ __forceinline__

// B_=2048 windows, N=64 tokens, C=256, H=8 heads, HD=32, NW=64 windows/image
static constexpr float kScale = 0.17677669529663687f;  // 32^-0.5

// Swizzled weight layout (wqkvT and wpT): [chunk][64 rows][512 B],
// chunk = 64 output-cols x 256 k. XOR bits 4..6 with row&7 (G4/T2).
DEVI size_t wswz(int chunk, int j, int b) {
  return (size_t)chunk * 32768 + (size_t)j * 512 + (size_t)(b ^ ((j & 7) << 4));
}

// ---------------- prep: swizzled weights + fused (rel-pos bias + mask) table ----
// biasM[w64][h][i][j] = bias_table[rel_index[i][j]][h] + mask[w64][i][j]   (f32, 8 MB)
__global__ __launch_bounds__(256) void prep_kernel(
    const float* __restrict__ wq, const float* __restrict__ bq,
    const float* __restrict__ wk, const float* __restrict__ bk,
    const float* __restrict__ wv, const float* __restrict__ bv,
    const float* __restrict__ wp,
    const float* __restrict__ bias_table, const int* __restrict__ rel_index,
    const float* __restrict__ mask,
    char* __restrict__ wqkvT, char* __restrict__ wpT,
    float* __restrict__ bqkv, float* __restrict__ biasM) {
  int idx = blockIdx.x * 256 + threadIdx.x;
  if (idx < 196608) {                       // 3*256*256  qkv weights
    int m = idx >> 16, rem = idx & 65535;
    int n = rem >> 8, k = rem & 255;
    const float* w = (m == 0) ? wq : (m == 1 ? wk : wv);
    float v = w[k * 256 + n];
    if (m == 0) v *= kScale;
    *(bf16*)(wqkvT + wswz(m * 4 + (n >> 6), n & 63, 2 * k)) = (bf16)v;
  } else if (idx < 262144) {                // + 256*256  proj weight
    int rem = idx - 196608;
    int n = rem >> 8, k = rem & 255;
    *(bf16*)(wpT + wswz(n >> 6, n & 63, 2 * k)) = (bf16)wp[k * 256 + n];
  } else if (idx < 262912) {                // + 3*256 biases
    int rem = idx - 262144;
    int m = rem >> 8, n = rem & 255;
    const float* b = (m == 0) ? bq : (m == 1 ? bk : bv);
    float v = b[n];
    if (m == 0) v *= kScale;
    bqkv[rem] = v;
  } else if (idx < 2360064) {               // + 64*8*64*64 fused bias+mask
    int rem = idx - 262912;
    int w = rem >> 15, h = (rem >> 12) & 7, ij = rem & 4095;
    biasM[rem] = bias_table[rel_index[ij] * 8 + h] + mask[w * 4096 + ij];
  }
}

// ---------------- kernel A: fused QKV projection (LDS-staged B) ----------------
// Q,K written in natural [row][col] layout; V written pre-transposed per window:
// vT[win][d][t]  (d=channel 0..255, t=token 0..63) for attn's V^T fragments.
__global__ __launch_bounds__(256) void qkv_kernel(
    const float* __restrict__ x, const char* __restrict__ wsz,
    const float* __restrict__ bqkv,
    bf16* __restrict__ qbuf, bf16* __restrict__ kbuf, bf16* __restrict__ vT) {
  __shared__ __align__(16) char bsm[32768];
  int tid = threadIdx.x;
  int w = tid >> 6, lane = tid & 63;
  int g = lane >> 4, c = lane & 15;
  size_t rowbase = (size_t)blockIdx.x * 128;

  bf16x8 af[2][8];
#pragma unroll
  for (int rt = 0; rt < 2; ++rt) {
    const float* xrow = x + (rowbase + w * 32 + rt * 16 + c) * 256;
#pragma unroll
    for (int kb = 0; kb < 8; ++kb) {
      const float4* p = (const float4*)(xrow + kb * 32 + g * 8);
      float4 f0 = p[0], f1 = p[1];
      bf16x8 a;
      a[0] = (bf16)f0.x; a[1] = (bf16)f0.y; a[2] = (bf16)f0.z; a[3] = (bf16)f0.w;
      a[4] = (bf16)f1.x; a[5] = (bf16)f1.y; a[6] = (bf16)f1.z; a[7] = (bf16)f1.w;
      af[rt][kb] = a;
    }
  }

  bf16x8 gr[8];
#pragma unroll
  for (int i = 0; i < 8; ++i)
    gr[i] = *(const bf16x8*)(wsz + (size_t)i * 4096 + (size_t)tid * 16);

  for (int cc = 0; cc < 12; ++cc) {
    int m = cc >> 2, nq = cc & 3;
    __syncthreads();
#pragma unroll
    for (int i = 0; i < 8; ++i)
      *(bf16x8*)(bsm + i * 4096 + tid * 16) = gr[i];
    if (cc < 11) {
      size_t base = (size_t)(cc + 1) * 32768;
#pragma unroll
      for (int i = 0; i < 8; ++i)
        gr[i] = *(const bf16x8*)(wsz + base + (size_t)i * 4096 + (size_t)tid * 16);
    }
    __syncthreads();

    f32x4 acc[2][4];
#pragma unroll
    for (int ct = 0; ct < 4; ++ct) {
      float b = bqkv[m * 256 + nq * 64 + ct * 16 + c];
      f32x4 a = {b, b, b, b};
      acc[0][ct] = a; acc[1][ct] = a;
    }
#pragma unroll
    for (int kb = 0; kb < 8; ++kb) {
      bf16x8 bf[4];
#pragma unroll
      for (int ct = 0; ct < 4; ++ct) {
        int j = ct * 16 + c;
        int off = (kb * 64 + g * 16) ^ ((j & 7) << 4);
        bf[ct] = *(const bf16x8*)(bsm + j * 512 + off);
      }
#pragma unroll
      for (int rt = 0; rt < 2; ++rt)
#pragma unroll
        for (int ct = 0; ct < 4; ++ct)
          acc[rt][ct] = __builtin_amdgcn_mfma_f32_16x16x32_bf16(af[rt][kb], bf[ct], acc[rt][ct], 0, 0, 0);
    }

    if (m < 2) {
      bf16* dst = (m == 0) ? qbuf : kbuf;
#pragma unroll
      for (int rt = 0; rt < 2; ++rt)
#pragma unroll
        for (int ct = 0; ct < 4; ++ct)
#pragma unroll
          for (int r = 0; r < 4; ++r)
            dst[(rowbase + w * 32 + rt * 16 + g * 4 + r) * 256 + nq * 64 + ct * 16 + c] =
                (bf16)acc[rt][ct][r];
    } else {
      // V transposed: vT[win][d][t], lane's 4 regs are 4 consecutive tokens
#pragma unroll
      for (int rt = 0; rt < 2; ++rt) {
        int tb = w * 32 + rt * 16;          // 0..112
        size_t win = blockIdx.x * 2 + (tb >> 6);
        int t0 = (tb & 63) + g * 4;
#pragma unroll
        for (int ct = 0; ct < 4; ++ct) {
          int d = nq * 64 + ct * 16 + c;
          bf16x4 pk;
          pk[0] = (bf16)acc[rt][ct][0]; pk[1] = (bf16)acc[rt][ct][1];
          pk[2] = (bf16)acc[rt][ct][2]; pk[3] = (bf16)acc[rt][ct][3];
          *(bf16x4*)(vT + win * 16384 + d * 64 + t0) = pk;
        }
      }
    }
  }
}

// ---------------- kernel B: per-window attention, swapped operands -------------
// Block = 1 window, 4 waves, ZERO barriers (all LDS wave-private).
// Wave wv handles heads {2wv, 2wv+1}.  mfma(K,Q) puts a q-row's scores
// lane-local (16 regs) -> softmax = lane-local max/sum + shfl_xor(16,32).
// P repacked through 2KB wave LDS; PV = mfma(V^T, P) -> packed 8B stores.
__global__ __launch_bounds__(256, 4) void attn_kernel(
    const bf16* __restrict__ qbuf, const bf16* __restrict__ kbuf,
    const bf16* __restrict__ vT, const float* __restrict__ biasM,
    bf16* __restrict__ obuf) {
  __shared__ __align__(16) char lds[40960];  // 4x8KB V^T slices + 4x2KB P bufs
  int tid = threadIdx.x;
  int wv = tid >> 6, lane = tid & 63;
  int g = lane >> 4, c = lane & 15;
  int win = blockIdx.x;
  char* vls = lds + wv * 8192;
  char* pbw = lds + 32768 + wv * 2048;

  // stage this wave's V^T slice [64 d][64 t] (its 2 heads), XOR-swizzled
  {
    const char* vg = (const char*)(vT + (size_t)win * 16384) + wv * 8192;
#pragma unroll
    for (int i = 0; i < 8; ++i) {
      int a = i * 1024 + lane * 16;
      bf16x8 t = *(const bf16x8*)(vg + a);
      *(bf16x8*)(vls + (a ^ (((a >> 7) & 7) << 4))) = t;
    }
  }
  // no __syncthreads: same-wave ds ops execute in order.

  for (int hh = 0; hh < 2; ++hh) {
    int h = wv * 2 + hh;
    const bf16* qb = qbuf + (size_t)win * 16384 + h * 32 + g * 8;
    const bf16* kb = kbuf + (size_t)win * 16384 + h * 32 + g * 8;
    bf16x8 kf[4];
#pragma unroll
    for (int mj = 0; mj < 4; ++mj)
      kf[mj] = *(const bf16x8*)(kb + (mj * 16 + c) * 256);
    const float* bmh = biasM + (((size_t)(win & 63) * 8 + h) * 64 + c) * 64 + g * 4;

#pragma unroll
    for (int mi = 0; mi < 4; ++mi) {
      bf16x8 qf = *(const bf16x8*)(qb + (mi * 16 + c) * 256);
      const f32x4 fz = {0.f, 0.f, 0.f, 0.f};
      f32x4 s[4];
#pragma unroll
      for (int mj = 0; mj < 4; ++mj) {
        f32x4 bm = *(const f32x4*)(bmh + mi * 1024 + mj * 16);
        s[mj] = __builtin_amdgcn_mfma_f32_16x16x32_bf16(kf[mj], qf, fz, 0, 0, 0);
        s[mj] += bm;
      }
      // row max: 16 lane-local + cross-g
      float mx;
      {
        f32x4 m4 = s[0];
        m4 = (f32x4){fmaxf(m4[0], s[1][0]), fmaxf(m4[1], s[1][1]),
                     fmaxf(m4[2], s[1][2]), fmaxf(m4[3], s[1][3])};
        m4 = (f32x4){fmaxf(m4[0], s[2][0]), fmaxf(m4[1], s[2][1]),
                     fmaxf(m4[2], s[2][2]), fmaxf(m4[3], s[2][3])};
        m4 = (f32x4){fmaxf(m4[0], s[3][0]), fmaxf(m4[1], s[3][1]),
                     fmaxf(m4[2], s[3][2]), fmaxf(m4[3], s[3][3])};
        mx = fmaxf(fmaxf(m4[0], m4[1]), fmaxf(m4[2], m4[3]));
        mx = fmaxf(mx, __shfl_xor(mx, 16));
        mx = fmaxf(mx, __shfl_xor(mx, 32));
      }
      // exp + row sum
      float sum;
      {
        f32x4 s4 = fz;
#pragma unroll
        for (int mj = 0; mj < 4; ++mj) {
#pragma unroll
          for (int r = 0; r < 4; ++r) s[mj][r] = __expf(s[mj][r] - mx);
          s4 += s[mj];
        }
        sum = (s4[0] + s4[1]) + (s4[2] + s4[3]);
        sum += __shfl_xor(sum, 16);
        sum += __shfl_xor(sum, 32);
      }
      float rs = 1.0f / sum;   // applied to the output, P stays unscaled (<=1)

      // pack P (bf16) into wave LDS: row c (q-local), k-major
#pragma unroll
      for (int mj = 0; mj < 4; ++mj) {
        bf16x4 pk;
        pk[0] = (bf16)s[mj][0]; pk[1] = (bf16)s[mj][1];
        pk[2] = (bf16)s[mj][2]; pk[3] = (bf16)s[mj][3];
        int a = c * 128 + mj * 32 + g * 8;
        *(bf16x4*)(pbw + (a ^ ((c & 7) << 4))) = pk;
      }
      // PV: out^T[d][q], A=V^T-frag (from vls), B=P-frag (from pbw)
      f32x4 o[2] = {fz, fz};
#pragma unroll
      for (int kb2 = 0; kb2 < 2; ++kb2) {
        int ap = (c * 128 + kb2 * 64 + g * 16) ^ ((c & 7) << 4);
        bf16x8 pf = *(const bf16x8*)(pbw + ap);
#pragma unroll
        for (int dt = 0; dt < 2; ++dt) {
          int d = hh * 32 + dt * 16 + c;
          int av = (d * 128 + kb2 * 64 + g * 16) ^ ((d & 7) << 4);
          bf16x8 vf = *(const bf16x8*)(vls + av);
          o[dt] = __builtin_amdgcn_mfma_f32_16x16x32_bf16(vf, pf, o[dt], 0, 0, 0);
        }
      }
      // scale by 1/sum (per q-row = per lane c) and store packed 8B
#pragma unroll
      for (int dt = 0; dt < 2; ++dt) {
        bf16x4 ov;
        ov[0] = (bf16)(o[dt][0] * rs); ov[1] = (bf16)(o[dt][1] * rs);
        ov[2] = (bf16)(o[dt][2] * rs); ov[3] = (bf16)(o[dt][3] * rs);
        *(bf16x4*)(obuf + (size_t)win * 16384 + (mi * 16 + c) * 256 + h * 32 + dt * 16 + g * 4) = ov;
      }
    }
  }
}

// ---------------- kernel C: output projection (LDS-staged B) ----------------
__global__ __launch_bounds__(256) void proj_kernel(
    const bf16* __restrict__ abuf, const char* __restrict__ wsz,
    const float* __restrict__ bp, float* __restrict__ out) {
  __shared__ __align__(16) char bsm[32768];
  int tid = threadIdx.x;
  int w = tid >> 6, lane = tid & 63;
  int g = lane >> 4, c = lane & 15;
  size_t rowbase = (size_t)blockIdx.x * 128;

  bf16x8 af[2][8];
#pragma unroll
  for (int rt = 0; rt < 2; ++rt) {
    const bf16* arow = abuf + (rowbase + w * 32 + rt * 16 + c) * 256;
#pragma unroll
    for (int kb = 0; kb < 8; ++kb)
      af[rt][kb] = *(const bf16x8*)(arow + kb * 32 + g * 8);
  }

  bf16x8 gr[8];
#pragma unroll
  for (int i = 0; i < 8; ++i)
    gr[i] = *(const bf16x8*)(wsz + (size_t)i * 4096 + (size_t)tid * 16);

  for (int cc = 0; cc < 4; ++cc) {
    __syncthreads();
#pragma unroll
    for (int i = 0; i < 8; ++i)
      *(bf16x8*)(bsm + i * 4096 + tid * 16) = gr[i];
    if (cc < 3) {
      size_t base = (size_t)(cc + 1) * 32768;
#pragma unroll
      for (int i = 0; i < 8; ++i)
        gr[i] = *(const bf16x8*)(wsz + base + (size_t)i * 4096 + (size_t)tid * 16);
    }
    __syncthreads();

    f32x4 acc[2][4];
#pragma unroll
    for (int ct = 0; ct < 4; ++ct) {
      float b = bp[cc * 64 + ct * 16 + c];
      f32x4 a = {b, b, b, b};
      acc[0][ct] = a; acc[1][ct] = a;
    }
#pragma unroll
    for (int kb = 0; kb < 8; ++kb) {
      bf16x8 bf[4];
#pragma unroll
      for (int ct = 0; ct < 4; ++ct) {
        int j = ct * 16 + c;
        int off = (kb * 64 + g * 16) ^ ((j & 7) << 4);
        bf[ct] = *(const bf16x8*)(bsm + j * 512 + off);
      }
#pragma unroll
      for (int rt = 0; rt < 2; ++rt)
#pragma unroll
        for (int ct = 0; ct < 4; ++ct)
          acc[rt][ct] = __builtin_amdgcn_mfma_f32_16x16x32_bf16(af[rt][kb], bf[ct], acc[rt][ct], 0, 0, 0);
    }

#pragma unroll
    for (int rt = 0; rt < 2; ++rt)
#pragma unroll
      for (int ct = 0; ct < 4; ++ct)
#pragma unroll
        for (int r = 0; r < 4; ++r)
          out[(rowbase + w * 32 + rt * 16 + g * 4 + r) * 256 + cc * 64 + ct * 16 + c] =
              acc[rt][ct][r];
  }
}

extern "C" void kernel_launch(void* const* d_in, const int* in_sizes, int n_in,
                              void* d_out, int out_size, void* d_ws, size_t ws_size,
                              hipStream_t stream) {
  const float* x          = (const float*)d_in[0];
  const float* mask       = (const float*)d_in[1];
  const float* wq         = (const float*)d_in[2];
  const float* bq         = (const float*)d_in[3];
  const float* wk         = (const float*)d_in[4];
  const float* bk         = (const float*)d_in[5];
  const float* wv         = (const float*)d_in[6];
  const float* bv         = (const float*)d_in[7];
  const float* wp         = (const float*)d_in[8];
  const float* bp         = (const float*)d_in[9];
  const float* bias_table = (const float*)d_in[10];
  const int*   rel_index  = (const int*)d_in[11];

  // Workspace (~75.6 MB): qbuf | wqkvT | wpT | bqkv | biasM
  char* ws = (char*)d_ws;
  size_t o = 0;
  bf16* qbuf = (bf16*)(ws + o); o += (size_t)2048 * 64 * 256 * 2;
  char* wqkvT = ws + o; o += (size_t)3 * 256 * 256 * 2;
  char* wpT = ws + o; o += (size_t)256 * 256 * 2;
  float* bqkv = (float*)(ws + o); o += (size_t)3 * 256 * 4;
  float* biasM = (float*)(ws + o); o += (size_t)64 * 8 * 64 * 64 * 4;
  if (ws_size < o) return;

  // vT, kbuf live in d_out (128 MB fp32); dead before proj_kernel overwrites.
  bf16* vT = (bf16*)d_out;
  bf16* kbuf = vT + (size_t)2048 * 64 * 256;

  prep_kernel<<<9219, 256, 0, stream>>>(wq, bq, wk, bk, wv, bv, wp,
                                        bias_table, rel_index, mask,
                                        wqkvT, wpT, bqkv, biasM);
  qkv_kernel<<<1024, 256, 0, stream>>>(x, wqkvT, bqkv, qbuf, kbuf, vT);
  attn_kernel<<<2048, 256, 0, stream>>>(qbuf, kbuf, vT, biasM, qbuf);
  proj_kernel<<<1024, 256, 0, stream>>>(qbuf, wpT, bp, (float*)d_out);
}

// Round 5
// 160.904 us; speedup vs baseline: 4.9843x; 1.3382x over previous
//
#include <hip/hip_runtime.h>
#include <hip/hip_bf16.h>

typedef __bf16 bf16;
typedef __bf16 bf16x4 __attribute__((ext_vector_type(4)));
typedef __bf16 bf16x8 __attribute__((ext_vector_type(8)));
typedef float  f32x4  __attribute__((ext_vector_type(4)));
typedef short  s16x4  __attribute__((ext_vector_type(4)));

#define DEVI __device__ __forceinline__

// B_=2048 windows, N=64 tokens, C=256, H=8 heads, HD=32, NW=64 windows/image
static constexpr float kScale = 0.17677669529663687f;  // 32^-0.5

DEVI f32x4 mfma32(bf16x8 a, bf16x8 b, f32x4 c) {
  return __builtin_amdgcn_mfma_f32_16x16x32_bf16(a, b, c, 0, 0, 0);
}
// K=16 bf16 MFMA (v_mfma_f32_16x16x16_bf16, A/B = 4 bf16 in 2 VGPRs).
// Builtin spelling on ROCm is the gfx90a-era "_1k" name; host pass (no amdgcn
// builtins) falls through to inline asm, which is parsed but never emitted
// (function is device-only).
DEVI f32x4 mfma16(bf16x4 a, bf16x4 b, f32x4 c) {
#if __has_builtin(__builtin_amdgcn_mfma_f32_16x16x16bf16_1k)
  return __builtin_amdgcn_mfma_f32_16x16x16bf16_1k(
      __builtin_bit_cast(s16x4, a), __builtin_bit_cast(s16x4, b), c, 0, 0, 0);
#else
  f32x4 d;
  asm volatile("v_mfma_f32_16x16x16_bf16 %0, %1, %2, %3"
               : "=v"(d)
               : "v"(a), "v"(b), "v"(c));
  return d;
#endif
}
DEVI bf16x4 pk4(f32x4 v) {
  bf16x4 p;
  p[0] = (bf16)v[0]; p[1] = (bf16)v[1]; p[2] = (bf16)v[2]; p[3] = (bf16)v[3];
  return p;
}

// ---------------- prep ----------------
// wstream: 12 chunks (m*4+kq) of [256 n][64 kk] bf16, row 128B, XOR-swizzled:
//   byte = chunk*32768 + n*128 + ((kk*2) ^ ((n&7)<<4)), value W_m[k=kq*64+kk][n]
//   (q-scale folded into m=0).
// wpstream: 4 chunks (kq) same layout for wp.
// bqkv[m][n] (q-scaled), biasM[w64][h][i][j] = bias_table[rel_index[i][j]][h]+mask.
__global__ __launch_bounds__(256) void prep_kernel(
    const float* __restrict__ wq, const float* __restrict__ bq,
    const float* __restrict__ wk, const float* __restrict__ bk,
    const float* __restrict__ wv, const float* __restrict__ bv,
    const float* __restrict__ wp,
    const float* __restrict__ bias_table, const int* __restrict__ rel_index,
    const float* __restrict__ mask,
    char* __restrict__ wstream, char* __restrict__ wpstream,
    float* __restrict__ bqkv, float* __restrict__ biasM) {
  int idx = blockIdx.x * 256 + threadIdx.x;
  if (idx < 196608) {                       // 3*256*256 qkv weights
    int m = idx >> 16, n = idx & 255, k = (idx >> 8) & 255;
    const float* w = (m == 0) ? wq : (m == 1 ? wk : wv);
    float v = w[k * 256 + n];
    if (m == 0) v *= kScale;
    *(bf16*)(wstream + (size_t)(m * 4 + (k >> 6)) * 32768 + n * 128 +
             (((k & 63) * 2) ^ ((n & 7) << 4))) = (bf16)v;
  } else if (idx < 262144) {                // + 256*256 proj weight
    int rem = idx - 196608;
    int n = rem & 255, k = (rem >> 8) & 255;
    *(bf16*)(wpstream + (size_t)(k >> 6) * 32768 + n * 128 +
             (((k & 63) * 2) ^ ((n & 7) << 4))) = (bf16)wp[k * 256 + n];
  } else if (idx < 262912) {                // + 3*256 biases
    int rem = idx - 262144;
    int m = rem >> 8, n = rem & 255;
    const float* b = (m == 0) ? bq : (m == 1 ? bk : bv);
    float v = b[n];
    if (m == 0) v *= kScale;
    bqkv[rem] = v;
  } else if (idx < 2360064) {               // + 64*8*64*64 fused bias+mask
    int rem = idx - 262912;
    int w = rem >> 15, h = (rem >> 12) & 7, ij = rem & 4095;
    biasM[rem] = bias_table[rel_index[ij] * 8 + h] + mask[w * 4096 + ij];
  }
}

// ---------------- fused swin attention block kernel ----------------
// Block = 1 window (64 tokens), 4 waves. Wave w owns output-channel slice
// [64w, 64w+64) = heads {2w, 2w+1} for ALL phases (QKV -> attn -> proj).
//
// QKV: x staged in LDS (32KB, bf16, XOR-swz); weight chunks [256n][64k]
//   streamed through 32KB LDS with reg prefetch. Q,K computed with SWAPPED
//   mfma(W,X) -> C[n][t]; V unswapped mfma(X,W) -> C[t][n]. The resulting
//   per-lane quads ARE the mfma_16x16x16 fragments needed by attention:
//   attention runs entirely in registers (no LDS, no shuffles).
// attn: S^T = mfma16(Kq, Qq) + biasM (C-init); lane-local softmax (+2 shfl);
//   P quads feed PV directly: O = mfma16(Vq, Pq). O -> obuf LDS (overlays x).
// proj: wp chunks streamed; A-frags from obuf; swapped mfma -> f32x4 stores.
__global__ __launch_bounds__(256, 2) void swin_kernel(
    const float* __restrict__ x, const char* __restrict__ wstream,
    const char* __restrict__ wpstream, const float* __restrict__ bqkv,
    const float* __restrict__ bp, const float* __restrict__ biasM,
    float* __restrict__ out) {
  __shared__ __align__(16) char xs_ob[32768];  // xs (QKV), then obuf
  __shared__ __align__(16) char wbuf[32768];   // weight chunk

  int tid = threadIdx.x;
  int w = tid >> 6, lane = tid & 63;
  int g = lane >> 4, c = lane & 15;
  int win = blockIdx.x;
  const f32x4 fz = {0.f, 0.f, 0.f, 0.f};

  // ---- stage x window -> bf16 LDS [64 t][256 k], rows 512B, XOR swz ----
  {
    const char* xw = (const char*)(x + (size_t)win * 16384);
#pragma unroll
    for (int i = 0; i < 8; ++i) {
      int gb = i * 8192 + tid * 32;
      float4 f0 = *(const float4*)(xw + gb);
      float4 f1 = *(const float4*)(xw + gb + 16);
      bf16x8 v;
      v[0] = (bf16)f0.x; v[1] = (bf16)f0.y; v[2] = (bf16)f0.z; v[3] = (bf16)f0.w;
      v[4] = (bf16)f1.x; v[5] = (bf16)f1.y; v[6] = (bf16)f1.z; v[7] = (bf16)f1.w;
      int t = gb >> 10, ir = (gb & 1023) >> 1;
      *(bf16x8*)(xs_ob + ((t * 512 + ir) ^ ((t & 7) << 4))) = v;
    }
  }
  // prefetch weight chunk 0
  bf16x8 gr[8];
#pragma unroll
  for (int i = 0; i < 8; ++i)
    gr[i] = *(const bf16x8*)(wstream + (size_t)i * 4096 + (size_t)tid * 16);

  bf16x4 qp[4][4], kp[4][4], vp[4][4];
  f32x4 acc[4][4];

  // ---- QKV: 12 chunks (m-major, kq 0..3 accumulate) ----
  for (int cc = 0; cc < 12; ++cc) {
    int m = cc >> 2, kq = cc & 3;
    __syncthreads();
#pragma unroll
    for (int i = 0; i < 8; ++i)
      *(bf16x8*)(wbuf + i * 4096 + tid * 16) = gr[i];
    if (cc < 11) {
      size_t base = (size_t)(cc + 1) * 32768;
#pragma unroll
      for (int i = 0; i < 8; ++i)
        gr[i] = *(const bf16x8*)(wstream + base + (size_t)i * 4096 + (size_t)tid * 16);
    } else {
#pragma unroll
      for (int i = 0; i < 8; ++i)
        gr[i] = *(const bf16x8*)(wpstream + (size_t)i * 4096 + (size_t)tid * 16);
    }
    __syncthreads();

    if (kq == 0) {
      if (m < 2) {
#pragma unroll
        for (int nt = 0; nt < 4; ++nt) {
          f32x4 b4 = *(const f32x4*)(bqkv + m * 256 + w * 64 + nt * 16 + g * 4);
#pragma unroll
          for (int tt = 0; tt < 4; ++tt) acc[tt][nt] = b4;
        }
      } else {
#pragma unroll
        for (int nt = 0; nt < 4; ++nt) {
          float bv_ = bqkv[512 + w * 64 + nt * 16 + c];
          f32x4 b4 = {bv_, bv_, bv_, bv_};
#pragma unroll
          for (int tt = 0; tt < 4; ++tt) acc[tt][nt] = b4;
        }
      }
    }
#pragma unroll
    for (int kb = 0; kb < 2; ++kb) {
      bf16x8 xf[4], wf[4];
#pragma unroll
      for (int tt = 0; tt < 4; ++tt)
        xf[tt] = *(const bf16x8*)(
            xs_ob + (((tt * 16 + c) * 512 + (kq * 64 + kb * 32 + g * 8) * 2) ^ ((c & 7) << 4)));
#pragma unroll
      for (int nt = 0; nt < 4; ++nt)
        wf[nt] = *(const bf16x8*)(
            wbuf + (w * 64 + nt * 16 + c) * 128 + ((kb * 64 + g * 16) ^ ((c & 7) << 4)));
      if (m < 2) {
#pragma unroll
        for (int tt = 0; tt < 4; ++tt)
#pragma unroll
          for (int nt = 0; nt < 4; ++nt)
            acc[tt][nt] = mfma32(wf[nt], xf[tt], acc[tt][nt]);
      } else {
#pragma unroll
        for (int tt = 0; tt < 4; ++tt)
#pragma unroll
          for (int nt = 0; nt < 4; ++nt)
            acc[tt][nt] = mfma32(xf[tt], wf[nt], acc[tt][nt]);
      }
    }
    if (kq == 3) {
#pragma unroll
      for (int tt = 0; tt < 4; ++tt)
#pragma unroll
        for (int nt = 0; nt < 4; ++nt) {
          if (m == 0)      qp[tt][nt] = pk4(acc[tt][nt]);
          else if (m == 1) kp[tt][nt] = pk4(acc[tt][nt]);
          else             vp[tt][nt] = pk4(acc[tt][nt]);
        }
    }
  }
  __syncthreads();  // xs reads done everywhere; xs_ob becomes obuf

  // ---- attention: fully in-register ----
#pragma unroll
  for (int hh = 0; hh < 2; ++hh) {
    int h = w * 2 + hh;
    const float* bm = biasM + ((size_t)(win & 63) * 8 + h) * 4096;
#pragma unroll
    for (int mi = 0; mi < 4; ++mi) {
      f32x4 s[4];
#pragma unroll
      for (int mj = 0; mj < 4; ++mj)
        s[mj] = *(const f32x4*)(bm + (mi * 16 + c) * 64 + mj * 16 + g * 4);
#pragma unroll
      for (int dd = 0; dd < 2; ++dd)
#pragma unroll
        for (int mj = 0; mj < 4; ++mj)
          s[mj] = mfma16(kp[mj][hh * 2 + dd], qp[mi][hh * 2 + dd], s[mj]);
      // softmax over this q-row's 64 scores (16 lane-local + xor16/32)
      float mx;
      {
        f32x4 m4 = s[0];
#pragma unroll
        for (int mj = 1; mj < 4; ++mj) {
          m4[0] = fmaxf(m4[0], s[mj][0]); m4[1] = fmaxf(m4[1], s[mj][1]);
          m4[2] = fmaxf(m4[2], s[mj][2]); m4[3] = fmaxf(m4[3], s[mj][3]);
        }
        mx = fmaxf(fmaxf(m4[0], m4[1]), fmaxf(m4[2], m4[3]));
        mx = fmaxf(mx, __shfl_xor(mx, 16));
        mx = fmaxf(mx, __shfl_xor(mx, 32));
      }
      float sum;
      {
        f32x4 s4 = fz;
#pragma unroll
        for (int mj = 0; mj < 4; ++mj) {
#pragma unroll
          for (int r = 0; r < 4; ++r) s[mj][r] = __expf(s[mj][r] - mx);
          s4 += s[mj];
        }
        sum = (s4[0] + s4[1]) + (s4[2] + s4[3]);
        sum += __shfl_xor(sum, 16);
        sum += __shfl_xor(sum, 32);
      }
      float rs = 1.0f / sum;
      bf16x4 pf[4];
#pragma unroll
      for (int mj = 0; mj < 4; ++mj) pf[mj] = pk4(s[mj]);
      // PV + scaled store to obuf
#pragma unroll
      for (int dt = 0; dt < 2; ++dt) {
        f32x4 o = fz;
#pragma unroll
        for (int mj = 0; mj < 4; ++mj)
          o = mfma16(vp[mj][hh * 2 + dt], pf[mj], o);
        bf16x4 ov;
        ov[0] = (bf16)(o[0] * rs); ov[1] = (bf16)(o[1] * rs);
        ov[2] = (bf16)(o[2] * rs); ov[3] = (bf16)(o[3] * rs);
        *(bf16x4*)(xs_ob + (((mi * 16 + c) * 512 + (h * 32 + dt * 16 + g * 4) * 2) ^
                            ((c & 7) << 4))) = ov;
      }
    }
  }

  // ---- projection: 4 wp chunks, accumulate over k ----
  f32x4 acc2[4][4];
#pragma unroll
  for (int nt = 0; nt < 4; ++nt) {
    f32x4 b4 = *(const f32x4*)(bp + w * 64 + nt * 16 + g * 4);
#pragma unroll
    for (int tt = 0; tt < 4; ++tt) acc2[tt][nt] = b4;
  }
  for (int cc = 0; cc < 4; ++cc) {
    __syncthreads();
#pragma unroll
    for (int i = 0; i < 8; ++i)
      *(bf16x8*)(wbuf + i * 4096 + tid * 16) = gr[i];
    if (cc < 3) {
      size_t base = (size_t)(cc + 1) * 32768;
#pragma unroll
      for (int i = 0; i < 8; ++i)
        gr[i] = *(const bf16x8*)(wpstream + base + (size_t)i * 4096 + (size_t)tid * 16);
    }
    __syncthreads();
#pragma unroll
    for (int kb = 0; kb < 2; ++kb) {
      bf16x8 of[4], wf[4];
#pragma unroll
      for (int tt = 0; tt < 4; ++tt)
        of[tt] = *(const bf16x8*)(
            xs_ob + (((tt * 16 + c) * 512 + (cc * 64 + kb * 32 + g * 8) * 2) ^ ((c & 7) << 4)));
#pragma unroll
      for (int nt = 0; nt < 4; ++nt)
        wf[nt] = *(const bf16x8*)(
            wbuf + (w * 64 + nt * 16 + c) * 128 + ((kb * 64 + g * 16) ^ ((c & 7) << 4)));
#pragma unroll
      for (int tt = 0; tt < 4; ++tt)
#pragma unroll
        for (int nt = 0; nt < 4; ++nt)
          acc2[tt][nt] = mfma32(wf[nt], of[tt], acc2[tt][nt]);
    }
  }
  // store: C[n][t] -> out[win*64 + t][n], f32x4 along n
#pragma unroll
  for (int tt = 0; tt < 4; ++tt)
#pragma unroll
    for (int nt = 0; nt < 4; ++nt)
      *(f32x4*)(out + ((size_t)win * 64 + tt * 16 + c) * 256 + w * 64 + nt * 16 + g * 4) =
          acc2[tt][nt];
}

extern "C" void kernel_launch(void* const* d_in, const int* in_sizes, int n_in,
                              void* d_out, int out_size, void* d_ws, size_t ws_size,
                              hipStream_t stream) {
  const float* x          = (const float*)d_in[0];
  const float* mask       = (const float*)d_in[1];
  const float* wq         = (const float*)d_in[2];
  const float* bq         = (const float*)d_in[3];
  const float* wk         = (const float*)d_in[4];
  const float* bk         = (const float*)d_in[5];
  const float* wv         = (const float*)d_in[6];
  const float* bv         = (const float*)d_in[7];
  const float* wp         = (const float*)d_in[8];
  const float* bp         = (const float*)d_in[9];
  const float* bias_table = (const float*)d_in[10];
  const int*   rel_index  = (const int*)d_in[11];

  // Workspace (~8.9 MB): wstream | wpstream | bqkv | biasM
  char* ws = (char*)d_ws;
  size_t o = 0;
  char* wstream = ws + o;  o += (size_t)12 * 32768;
  char* wpstream = ws + o; o += (size_t)4 * 32768;
  float* bqkv = (float*)(ws + o); o += (size_t)768 * 4;
  float* biasM = (float*)(ws + o); o += (size_t)64 * 8 * 64 * 64 * 4;
  if (ws_size < o) return;

  prep_kernel<<<9219, 256, 0, stream>>>(wq, bq, wk, bk, wv, bv, wp,
                                        bias_table, rel_index, mask,
                                        wstream, wpstream, bqkv, biasM);
  swin_kernel<<<2048, 256, 0, stream>>>(x, wstream, wpstream, bqkv, bp, biasM,
                                        (float*)d_out);
}